// Round 3
// baseline (1412.777 us; speedup 1.0000x reference)
//
#include <hip/hip_runtime.h>
#include <hip/hip_bf16.h>

// MPAttentionInflationBlock on MI355X — round 3.
// Device buffers: f32 in / f32 out (round-2 NaN proved f32 inputs; npz sizes
// corroborate). Internal: bf16 activations + bf16 MFMA w/ f32 accum; QKV chunk
// kept f32 for accuracy margin; attention fully f32. ws layout identical to
// round 2 (117,964,800 B — proven to pass the ws_size guard).

typedef __attribute__((ext_vector_type(8))) __bf16 bf16x8;
typedef __attribute__((ext_vector_type(4))) float  f32x4;

#define MP_NEW 0.9191450300180579f   // 0.7 / sqrt(0.58)
#define MP_RES 0.3939192985791677f   // 0.3 / sqrt(0.58)

__device__ __forceinline__ __hip_bfloat16 f2b(float x) { return __float2bfloat16(x); }
__device__ __forceinline__ float b2f(__hip_bfloat16 x) { return __bfloat162float(x); }

#define GLOAD16(g, l)                                                             \
  __builtin_amdgcn_global_load_lds((const __attribute__((address_space(1))) void*)(g), \
                                   (__attribute__((address_space(3))) void*)(l), 16, 0, 0)

// -------- diagnostic fallback: ws too small -> unmistakable output --------
__global__ __launch_bounds__(256)
void fill_kernel(float* o, int n)
{
  int i = blockIdx.x * 256 + threadIdx.x;
  if (i < n) o[i] = 12345.0f;
}

// -------- weight row-l2norm: wn = w/max(||w||,1e-4)/sqrt(512), f32->bf16 --------
__global__ __launch_bounds__(64)
void wnorm_pack(const float* __restrict__ w, __hip_bfloat16* __restrict__ o)
{
  const int r = blockIdx.x, lane = threadIdx.x;
  const float* wr = w + (size_t)r * 512;
  float x[8], s = 0.f;
  #pragma unroll
  for (int e = 0; e < 8; ++e) { x[e] = wr[e * 64 + lane]; s += x[e] * x[e]; }
  #pragma unroll
  for (int m = 1; m < 64; m <<= 1) s += __shfl_xor(s, m);
  const float scale = 1.0f / (fmaxf(sqrtf(s), 1e-4f) * 22.62741699796952f); // *sqrt(512)
  #pragma unroll
  for (int e = 0; e < 8; ++e) o[(size_t)r * 512 + e * 64 + lane] = f2b(x[e] * scale);
}

// -------- x[b,c,t,h,w] (f32) -> Y0[m][c] (bf16 token-major) --------
__global__ __launch_bounds__(256)
void transpose_in(const float* __restrict__ x, __hip_bfloat16* __restrict__ Y0)
{
  __shared__ float tile[32][33];
  const int tx = threadIdx.x, ty = threadIdx.y;
  const int hh = blockIdx.x;
  const int c0 = blockIdx.y * 32;
  const int bt = blockIdx.z;
  const int b = bt >> 4, t = bt & 15;
  const float* xb = x + (size_t)b * 8388608 + (size_t)t * 1024 + hh * 32 + tx;
  #pragma unroll
  for (int r = 0; r < 4; ++r) {
    const int cc = ty * 4 + r;
    tile[tx][cc] = xb[(size_t)(c0 + cc) * 16384];   // 32 consecutive w: coalesced
  }
  __syncthreads();
  #pragma unroll
  for (int r = 0; r < 4; ++r) {
    const int w = ty * 4 + r;
    const size_t m = ((size_t)b * 1024 + hh * 32 + w) * 16 + t;
    Y0[m * 512 + c0 + tx] = f2b(tile[w][tx]);       // 32 consecutive c: coalesced
  }
}

// -------- Yf[m][c] (bf16) -> out[b,c,t,h,w] (f32) --------
__global__ __launch_bounds__(256)
void transpose_out(const __hip_bfloat16* __restrict__ Yf, float* __restrict__ out)
{
  __shared__ __align__(16) __hip_bfloat16 tile[32][33];
  const int tx = threadIdx.x, ty = threadIdx.y;
  const int hh = blockIdx.x;
  const int c0 = blockIdx.y * 32;
  const int bt = blockIdx.z;
  const int b = bt >> 4, t = bt & 15;
  #pragma unroll
  for (int r = 0; r < 4; ++r) {
    const int w = ty * 4 + r;
    const size_t m = ((size_t)b * 1024 + hh * 32 + w) * 16 + t;
    tile[w][tx] = Yf[m * 512 + c0 + tx];
  }
  __syncthreads();
  float* ob = out + (size_t)b * 8388608 + (size_t)t * 1024 + hh * 32 + tx;
  #pragma unroll
  for (int r = 0; r < 4; ++r) {
    const int cc = ty * 4 + r;
    ob[(size_t)(c0 + cc) * 16384] = b2f(tile[tx][cc]);
  }
}

// -------- fp32 attention: one wave per (seq, head); 20 keys (4 mem + 16) --------
// QKV: [chunk_rows][1536] f32 (cols: q 0..511 | k 512..1023 | v 1024..1535, h*64+d)
__global__ __launch_bounds__(64)
void attn_kernel(const float* __restrict__ QKV, const float* __restrict__ mkv,
                 __hip_bfloat16* __restrict__ AOUT)
{
  __shared__ __align__(16) float Qs[16][68];
  __shared__ __align__(16) float Ks[20][68];
  __shared__ __align__(16) float Ps[16 * 20];
  const int lane = threadIdx.x;                  // = d
  const int bh = blockIdx.x;
  const int seq = bh >> 3, h = bh & 7;           // seq local to chunk
  const float* qb = QKV + (size_t)seq * 16 * 1536 + h * 64 + lane;

  float q[16], k[20], v[20];
  #pragma unroll
  for (int i = 0; i < 16; ++i) q[i] = qb[(size_t)i * 1536];
  #pragma unroll
  for (int j = 0; j < 4; ++j) {
    k[j] = mkv[(h * 4 + j) * 64 + lane];          // mem_kv[l][0][h][j][d]
    v[j] = mkv[2048 + (h * 4 + j) * 64 + lane];   // mem_kv[l][1][h][j][d]
  }
  #pragma unroll
  for (int j = 0; j < 16; ++j) {
    k[4 + j] = qb[(size_t)j * 1536 + 512];
    v[4 + j] = qb[(size_t)j * 1536 + 1024];
  }

  // pixel_norm: q net scale 1/max(||q||,eps); k,v: 8/max(||.||,eps)
  #pragma unroll
  for (int i = 0; i < 16; ++i) {
    float s = q[i] * q[i];
    #pragma unroll
    for (int m = 1; m < 64; m <<= 1) s += __shfl_xor(s, m);
    q[i] *= 1.0f / fmaxf(sqrtf(s), 1e-4f);
    Qs[i][lane] = q[i];
  }
  #pragma unroll
  for (int j = 0; j < 20; ++j) {
    float s = k[j] * k[j];
    #pragma unroll
    for (int m = 1; m < 64; m <<= 1) s += __shfl_xor(s, m);
    k[j] *= 8.0f / fmaxf(sqrtf(s), 1e-4f);
    Ks[j][lane] = k[j];
    float sv = v[j] * v[j];
    #pragma unroll
    for (int m = 1; m < 64; m <<= 1) sv += __shfl_xor(sv, m);
    v[j] *= 8.0f / fmaxf(sqrtf(sv), 1e-4f);
  }
  __syncthreads();

  // sim[i][j]: 320 pairs over 64 lanes -> 5 per lane, float4 LDS dot products
  #pragma unroll
  for (int pp = 0; pp < 5; ++pp) {
    const int p = lane + (pp << 6);
    const int i = p / 20;
    const int j = p - i * 20;
    float s = 0.f;
    #pragma unroll
    for (int d4 = 0; d4 < 16; ++d4) {
      float4 qv = *(const float4*)&Qs[i][d4 * 4];
      float4 kv = *(const float4*)&Ks[j][d4 * 4];
      s += qv.x * kv.x + qv.y * kv.y + qv.z * kv.z + qv.w * kv.w;
    }
    Ps[i * 20 + j] = s;
  }
  __syncthreads();

  // row softmax (16 rows on lanes 0..15; 20-wide, tiny)
  if (lane < 16) {
    float mx = -1e30f;
    #pragma unroll
    for (int j = 0; j < 20; ++j) mx = fmaxf(mx, Ps[lane * 20 + j]);
    float e[20], ssum = 0.f;
    #pragma unroll
    for (int j = 0; j < 20; ++j) { e[j] = expf(Ps[lane * 20 + j] - mx); ssum += e[j]; }
    const float inv = 1.0f / ssum;
    #pragma unroll
    for (int j = 0; j < 20; ++j) Ps[lane * 20 + j] = e[j] * inv;
  }
  __syncthreads();

  // out[i][d] = sum_j P[i][j] * v[j][d] -> bf16 [m][512] at column h*64+d
  __hip_bfloat16* ob = AOUT + (size_t)seq * 16 * 512 + h * 64 + lane;
  #pragma unroll
  for (int i = 0; i < 16; ++i) {
    float s = 0.f;
    #pragma unroll
    for (int j = 0; j < 20; ++j) s += Ps[i * 20 + j] * v[j];   // broadcast LDS reads
    ob[(size_t)i * 512] = f2b(s);
  }
}

// -------- bf16 gemm_bt: C[m][n] = sum_k A[m][k] * Bw[n][k], K=512 --------
// MODE 0: write f32 C to Cq (ld 1536)                                  [QKV]
// MODE 1: y = MP_NEW*C + MP_RES*res; yout bf16 (ld 512)                [out-proj]
// MODE 2: y = MP_NEW*(C*gain) + MP_RES*res; yout bf16                  [final proj]
template<int MODE>
__global__ __launch_bounds__(256)
void gemm3(const __hip_bfloat16* __restrict__ A, const __hip_bfloat16* __restrict__ Bw,
           float* __restrict__ Cq, const __hip_bfloat16* res,
           __hip_bfloat16* yout, const float* __restrict__ gainp)
{
  __shared__ __hip_bfloat16 sA[128 * 64];
  __shared__ __hip_bfloat16 sB[128 * 64];
  const int bn = blockIdx.x, bm = blockIdx.y;
  const int tid = threadIdx.x;
  const int wid = tid >> 6, lane = tid & 63;
  const int wrow = wid >> 1, wcol = wid & 1;
  const int fr = lane & 15, fq = lane >> 4;
  const int rowL = tid >> 3;            // 0..31
  const int colL = (tid & 7) * 8;       // 0..56

  const size_t K = 512;
  const __hip_bfloat16* Ab = A  + (size_t)bm * 128 * K;
  const __hip_bfloat16* Bb = Bw + (size_t)bn * 128 * K;

  f32x4 acc[4][4];
  const f32x4 zz = {0.f, 0.f, 0.f, 0.f};
  #pragma unroll
  for (int i = 0; i < 4; ++i)
    #pragma unroll
    for (int j = 0; j < 4; ++j) acc[i][j] = zz;

  for (int ks = 0; ks < 8; ++ks) {
    const int k0 = ks * 64;
    __syncthreads();
    #pragma unroll
    for (int call = 0; call < 4; ++call) {
      const __hip_bfloat16* ga = Ab + (size_t)(call * 32 + rowL) * K + k0 + colL;
      GLOAD16(ga, (char*)sA + call * 4096 + wid * 1024);
    }
    #pragma unroll
    for (int call = 0; call < 4; ++call) {
      const __hip_bfloat16* gb = Bb + (size_t)(call * 32 + rowL) * K + k0 + colL;
      GLOAD16(gb, (char*)sB + call * 4096 + wid * 1024);
    }
    __syncthreads();   // compiler drains vmcnt before barrier -> LDS tiles ready

    const bf16x8* pA = (const bf16x8*)sA;
    const bf16x8* pB = (const bf16x8*)sB;
    #pragma unroll
    for (int kk = 0; kk < 2; ++kk) {
      bf16x8 af[4], bfv[4];
      #pragma unroll
      for (int fi = 0; fi < 4; ++fi)
        af[fi] = pA[((wrow * 64 + fi * 16 + fr) * 64 + kk * 32 + fq * 8) >> 3];
      #pragma unroll
      for (int fj = 0; fj < 4; ++fj)
        bfv[fj] = pB[((wcol * 64 + fj * 16 + fr) * 64 + kk * 32 + fq * 8) >> 3];
      #pragma unroll
      for (int fi = 0; fi < 4; ++fi)
        #pragma unroll
        for (int fj = 0; fj < 4; ++fj)
          acc[fi][fj] = __builtin_amdgcn_mfma_f32_16x16x32_bf16(af[fi], bfv[fj], acc[fi][fj], 0, 0, 0);
    }
  }

  float g = 0.f;
  if (MODE == 2) g = gainp[0];

  #pragma unroll
  for (int fi = 0; fi < 4; ++fi) {
    #pragma unroll
    for (int fj = 0; fj < 4; ++fj) {
      #pragma unroll
      for (int jj = 0; jj < 4; ++jj) {
        const int gm = bm * 128 + wrow * 64 + fi * 16 + fq * 4 + jj;
        const int gn = bn * 128 + wcol * 64 + fj * 16 + fr;
        const float c = acc[fi][fj][jj];
        if constexpr (MODE == 0) {
          Cq[(size_t)gm * 1536 + gn] = c;
        } else if constexpr (MODE == 1) {
          const float y = MP_NEW * c + MP_RES * b2f(res[(size_t)gm * 512 + gn]);
          yout[(size_t)gm * 512 + gn] = f2b(y);
        } else {
          const float y = MP_NEW * (c * g) + MP_RES * b2f(res[(size_t)gm * 512 + gn]);
          yout[(size_t)gm * 512 + gn] = f2b(y);
        }
      }
    }
  }
}

extern "C" void kernel_launch(void* const* d_in, const int* in_sizes, int n_in,
                              void* d_out, int out_size, void* d_ws, size_t ws_size,
                              hipStream_t stream)
{
  const float* x     = (const float*)d_in[0];
  const float* wqkv  = (const float*)d_in[1];
  const float* wout  = (const float*)d_in[2];
  const float* mkv   = (const float*)d_in[3];
  const float* wproj = (const float*)d_in[4];
  const float* gain  = (const float*)d_in[5];
  float* out = (float*)d_out;

  // workspace layout (bytes), total 117,964,800 (identical to round 2 - proven)
  char* ws = (char*)d_ws;
  __hip_bfloat16* Y0   = (__hip_bfloat16*)(ws + 0);           // 33,554,432
  __hip_bfloat16* Ycur = (__hip_bfloat16*)(ws + 33554432);    // 33,554,432
  __hip_bfloat16* AOUT = (__hip_bfloat16*)(ws + 67108864);    // 33,554,432
  float*          QKVc = (float*)(ws + 100663296);            // 12,582,912 (2048x1536 f32 chunk)
  __hip_bfloat16* WQ   = (__hip_bfloat16*)(ws + 113246208);   //  3,145,728
  __hip_bfloat16* WO   = (__hip_bfloat16*)(ws + 116391936);   //  1,048,576
  __hip_bfloat16* WP   = (__hip_bfloat16*)(ws + 117440512);   //    524,288

  if (ws_size < 117964800ULL) {
    // unmistakable diagnostic signature: absmax ~12345
    fill_kernel<<<(out_size + 255) / 256, 256, 0, stream>>>(out, out_size);
    return;
  }

  // normalize all weight rows (f32 -> bf16)
  wnorm_pack<<<1536, 64, 0, stream>>>(wqkv,           WQ);
  wnorm_pack<<<1536, 64, 0, stream>>>(wqkv + 786432,  WQ + 786432);
  wnorm_pack<<<512,  64, 0, stream>>>(wout,           WO);
  wnorm_pack<<<512,  64, 0, stream>>>(wout + 262144,  WO + 262144);
  wnorm_pack<<<512,  64, 0, stream>>>(wproj,          WP);

  // x (f32) -> token-major bf16
  transpose_in<<<dim3(32, 16, 32), dim3(32, 8), 0, stream>>>(x, Y0);

  const int M = 32768, CH = 2048, NCH = M / CH;
  for (int layer = 0; layer < 2; ++layer) {
    const __hip_bfloat16* WQl = WQ + (size_t)layer * 786432;
    const __hip_bfloat16* WOl = WO + (size_t)layer * 262144;
    const float* mk  = mkv + (size_t)layer * 4096;
    __hip_bfloat16* Acur = (layer == 0) ? Y0 : Ycur;
    for (int ch = 0; ch < NCH; ++ch) {
      const size_t m0 = (size_t)ch * CH;
      gemm3<0><<<dim3(12, CH / 128), 256, 0, stream>>>(Acur + m0 * 512, WQl, QKVc,
                                                       nullptr, nullptr, nullptr);
      attn_kernel<<<(CH / 16) * 8, 64, 0, stream>>>(QKVc, mk, AOUT + m0 * 512);
    }
    // y = mp_add(out_proj(AOUT), Acur) -> Ycur  (layer 1: in-place-safe, 1:1 element map)
    gemm3<1><<<dim3(4, 256), 256, 0, stream>>>(AOUT, WOl, nullptr, Acur, Ycur, nullptr);
  }

  // final: y = mp_add(proj(Ycur)*gain, Y0) -> AOUT (reused), then transpose out (f32)
  gemm3<2><<<dim3(4, 256), 256, 0, stream>>>(Ycur, WP, nullptr, Y0, AOUT, gain);
  transpose_out<<<dim3(32, 16, 32), dim3(32, 8), 0, stream>>>(AOUT, out);
}

// Round 4
// 735.435 us; speedup vs baseline: 1.9210x; 1.9210x over previous
//
#include <hip/hip_runtime.h>
#include <hip/hip_bf16.h>

// MPAttentionInflationBlock on MI355X — round 4.
// f32 in / f32 out device buffers; internal bf16 MFMA w/ f32 accum.
// Changes vs round 3 (which passed, 1413us, absmax 0.0078):
//  - CH=8192 chunks (4/layer, was 16), QKV chunk bf16, attention writes its
//    output IN-PLACE over its head's q-columns -> AOUT buffer eliminated
//  - T2 LDS swizzle (pre-swizzled global source + swizzled ds_read; linear
//    global_load_lds dest per rule #21) -> kills 16-way bank conflicts
//  - T1 XCD-aware block swizzle on all gemm grids (nwg%8==0 everywhere)
//  - out-proj per chunk (A from QKV buffer, lda=1536); final mp_add in-place
//  - ws total 96,993,280 B (< proven 117,964,800)

typedef __attribute__((ext_vector_type(8))) __bf16 bf16x8;
typedef __attribute__((ext_vector_type(4))) float  f32x4;

#define MP_NEW 0.9191450300180579f   // 0.7 / sqrt(0.58)
#define MP_RES 0.3939192985791677f   // 0.3 / sqrt(0.58)

__device__ __forceinline__ __hip_bfloat16 f2b(float x) { return __float2bfloat16(x); }
__device__ __forceinline__ float b2f(__hip_bfloat16 x) { return __bfloat162float(x); }

#define GLOAD16(g, l)                                                             \
  __builtin_amdgcn_global_load_lds((const __attribute__((address_space(1))) void*)(g), \
                                   (__attribute__((address_space(3))) void*)(l), 16, 0, 0)

// -------- diagnostic fallback: ws too small -> unmistakable output --------
__global__ __launch_bounds__(256)
void fill_kernel(float* o, int n)
{
  int i = blockIdx.x * 256 + threadIdx.x;
  if (i < n) o[i] = 12345.0f;
}

// -------- weight row-l2norm: wn = w/max(||w||,1e-4)/sqrt(512), f32->bf16 --------
__global__ __launch_bounds__(64)
void wnorm_pack(const float* __restrict__ w, __hip_bfloat16* __restrict__ o)
{
  const int r = blockIdx.x, lane = threadIdx.x;
  const float* wr = w + (size_t)r * 512;
  float x[8], s = 0.f;
  #pragma unroll
  for (int e = 0; e < 8; ++e) { x[e] = wr[e * 64 + lane]; s += x[e] * x[e]; }
  #pragma unroll
  for (int m = 1; m < 64; m <<= 1) s += __shfl_xor(s, m);
  const float scale = 1.0f / (fmaxf(sqrtf(s), 1e-4f) * 22.62741699796952f); // *sqrt(512)
  #pragma unroll
  for (int e = 0; e < 8; ++e) o[(size_t)r * 512 + e * 64 + lane] = f2b(x[e] * scale);
}

// -------- x[b,c,t,h,w] (f32) -> Y0[m][c] (bf16 token-major) --------
__global__ __launch_bounds__(256)
void transpose_in(const float* __restrict__ x, __hip_bfloat16* __restrict__ Y0)
{
  __shared__ float tile[32][33];
  const int tx = threadIdx.x, ty = threadIdx.y;
  const int hh = blockIdx.x;
  const int c0 = blockIdx.y * 32;
  const int bt = blockIdx.z;
  const int b = bt >> 4, t = bt & 15;
  const float* xb = x + (size_t)b * 8388608 + (size_t)t * 1024 + hh * 32 + tx;
  #pragma unroll
  for (int r = 0; r < 4; ++r) {
    const int cc = ty * 4 + r;
    tile[tx][cc] = xb[(size_t)(c0 + cc) * 16384];   // 32 consecutive w: coalesced
  }
  __syncthreads();
  #pragma unroll
  for (int r = 0; r < 4; ++r) {
    const int w = ty * 4 + r;
    const size_t m = ((size_t)b * 1024 + hh * 32 + w) * 16 + t;
    Y0[m * 512 + c0 + tx] = f2b(tile[w][tx]);       // 32 consecutive c: coalesced
  }
}

// -------- Yf[m][c] (bf16) -> out[b,c,t,h,w] (f32) --------
__global__ __launch_bounds__(256)
void transpose_out(const __hip_bfloat16* __restrict__ Yf, float* __restrict__ out)
{
  __shared__ __align__(16) __hip_bfloat16 tile[32][33];
  const int tx = threadIdx.x, ty = threadIdx.y;
  const int hh = blockIdx.x;
  const int c0 = blockIdx.y * 32;
  const int bt = blockIdx.z;
  const int b = bt >> 4, t = bt & 15;
  #pragma unroll
  for (int r = 0; r < 4; ++r) {
    const int w = ty * 4 + r;
    const size_t m = ((size_t)b * 1024 + hh * 32 + w) * 16 + t;
    tile[w][tx] = Yf[m * 512 + c0 + tx];
  }
  __syncthreads();
  float* ob = out + (size_t)b * 8388608 + (size_t)t * 1024 + hh * 32 + tx;
  #pragma unroll
  for (int r = 0; r < 4; ++r) {
    const int cc = ty * 4 + r;
    ob[(size_t)(c0 + cc) * 16384] = b2f(tile[tx][cc]);
  }
}

// -------- fp32 attention, one wave per (seq, head); 20 keys (4 mem + 16) --------
// QKV: [chunk_rows][1536] bf16; writes output in-place over its head's q-cols.
__global__ __launch_bounds__(64)
void attn_kernel(__hip_bfloat16* __restrict__ QKV, const float* __restrict__ mkv)
{
  __shared__ __align__(16) float Qs[16][68];
  __shared__ __align__(16) float Ks[20][68];
  __shared__ __align__(16) float Ps[16 * 20];
  const int lane = threadIdx.x;                  // = d
  const int bh = blockIdx.x;
  const int seq = bh >> 3, h = bh & 7;           // seq local to chunk
  __hip_bfloat16* qb = QKV + (size_t)seq * 16 * 1536 + h * 64 + lane;

  float q[16], k[20], v[20];
  #pragma unroll
  for (int i = 0; i < 16; ++i) q[i] = b2f(qb[(size_t)i * 1536]);
  #pragma unroll
  for (int j = 0; j < 4; ++j) {
    k[j] = mkv[(h * 4 + j) * 64 + lane];          // mem_kv[l][0][h][j][d]  (f32)
    v[j] = mkv[2048 + (h * 4 + j) * 64 + lane];   // mem_kv[l][1][h][j][d]
  }
  #pragma unroll
  for (int j = 0; j < 16; ++j) {
    k[4 + j] = b2f(qb[(size_t)j * 1536 + 512]);
    v[4 + j] = b2f(qb[(size_t)j * 1536 + 1024]);
  }

  // pixel_norm: q net scale 1/max(||q||,eps); k,v: 8/max(||.||,eps)
  #pragma unroll
  for (int i = 0; i < 16; ++i) {
    float s = q[i] * q[i];
    #pragma unroll
    for (int m = 1; m < 64; m <<= 1) s += __shfl_xor(s, m);
    q[i] *= 1.0f / fmaxf(sqrtf(s), 1e-4f);
    Qs[i][lane] = q[i];
  }
  #pragma unroll
  for (int j = 0; j < 20; ++j) {
    float s = k[j] * k[j];
    #pragma unroll
    for (int m = 1; m < 64; m <<= 1) s += __shfl_xor(s, m);
    k[j] *= 8.0f / fmaxf(sqrtf(s), 1e-4f);
    Ks[j][lane] = k[j];
    float sv = v[j] * v[j];
    #pragma unroll
    for (int m = 1; m < 64; m <<= 1) sv += __shfl_xor(sv, m);
    v[j] *= 8.0f / fmaxf(sqrtf(sv), 1e-4f);
  }
  __syncthreads();

  // sim[i][j]: 320 pairs over 64 lanes -> 5 per lane, float4 LDS dot products
  #pragma unroll
  for (int pp = 0; pp < 5; ++pp) {
    const int p = lane + (pp << 6);
    const int i = p / 20;
    const int j = p - i * 20;
    float s = 0.f;
    #pragma unroll
    for (int d4 = 0; d4 < 16; ++d4) {
      float4 qv = *(const float4*)&Qs[i][d4 * 4];
      float4 kv = *(const float4*)&Ks[j][d4 * 4];
      s += qv.x * kv.x + qv.y * kv.y + qv.z * kv.z + qv.w * kv.w;
    }
    Ps[i * 20 + j] = s;
  }
  __syncthreads();

  // row softmax (16 rows on lanes 0..15; 20-wide, tiny)
  if (lane < 16) {
    float mx = -1e30f;
    #pragma unroll
    for (int j = 0; j < 20; ++j) mx = fmaxf(mx, Ps[lane * 20 + j]);
    float e[20], ssum = 0.f;
    #pragma unroll
    for (int j = 0; j < 20; ++j) { e[j] = expf(Ps[lane * 20 + j] - mx); ssum += e[j]; }
    const float inv = 1.0f / ssum;
    #pragma unroll
    for (int j = 0; j < 20; ++j) Ps[lane * 20 + j] = e[j] * inv;
  }
  __syncthreads();

  // out[i][d] = sum_j P[i][j]*v[j][d] -> overwrite q-cols (safe: this block
  // is the only reader/writer of (seq, head h) columns)
  #pragma unroll
  for (int i = 0; i < 16; ++i) {
    float s = 0.f;
    #pragma unroll
    for (int j = 0; j < 20; ++j) s += Ps[i * 20 + j] * v[j];   // broadcast LDS reads
    qb[(size_t)i * 1536] = f2b(s);
  }
}

// -------- bf16 gemm_bt: C[m][n] = sum_k A[m][k]*Bw[n][k], K=512, 128x128 tile --------
// T2 swizzle: LDS dest linear (global_load_lds), global source column
// pre-swizzled, ds_read index swizzled (rule #21: same involution both sides).
// MODE 0: out[gm*ldo+gn] = C                                  [QKV, ldo=1536]
// MODE 1: out = MP_NEW*C + MP_RES*res                         [out-proj, ldo=512]
// MODE 2: out = MP_NEW*(C*gain) + MP_RES*res                  [final proj]
template<int MODE>
__global__ __launch_bounds__(256)
void gemm3(const __hip_bfloat16* __restrict__ A, const __hip_bfloat16* __restrict__ Bw,
           int lda, __hip_bfloat16* __restrict__ outp, int ldo,
           const __hip_bfloat16* __restrict__ res, const float* __restrict__ gainp)
{
  __shared__ __hip_bfloat16 sA[128 * 64];
  __shared__ __hip_bfloat16 sB[128 * 64];
  // T1: XCD-aware bijective block swizzle (all grids have nwg % 8 == 0)
  const int nwg = gridDim.x * gridDim.y;
  int bid = blockIdx.y * gridDim.x + blockIdx.x;
  bid = (bid & 7) * (nwg >> 3) + (bid >> 3);
  const int bn = bid % gridDim.x, bm = bid / gridDim.x;

  const int tid = threadIdx.x;
  const int wid = tid >> 6, lane = tid & 63;
  const int wrow = wid >> 1, wcol = wid & 1;
  const int fr = lane & 15, fq = lane >> 4;
  const int rowL = tid >> 3;                       // 0..31 (row within 32-row stage group)
  const int colSwz = (((tid & 7) ^ (rowL & 7)) * 8); // T2 pre-swizzled source col (elements)

  const __hip_bfloat16* Ab = A  + (size_t)bm * 128 * lda;
  const __hip_bfloat16* Bb = Bw + (size_t)bn * 128 * 512;

  f32x4 acc[4][4];
  const f32x4 zz = {0.f, 0.f, 0.f, 0.f};
  #pragma unroll
  for (int i = 0; i < 4; ++i)
    #pragma unroll
    for (int j = 0; j < 4; ++j) acc[i][j] = zz;

  for (int ks = 0; ks < 8; ++ks) {
    const int k0 = ks * 64;
    __syncthreads();
    #pragma unroll
    for (int call = 0; call < 4; ++call) {
      const __hip_bfloat16* ga = Ab + (size_t)(call * 32 + rowL) * lda + k0 + colSwz;
      GLOAD16(ga, (char*)sA + call * 4096 + wid * 1024);
    }
    #pragma unroll
    for (int call = 0; call < 4; ++call) {
      const __hip_bfloat16* gb = Bb + (size_t)(call * 32 + rowL) * 512 + k0 + colSwz;
      GLOAD16(gb, (char*)sB + call * 4096 + wid * 1024);
    }
    __syncthreads();   // compiler drains vmcnt before barrier -> LDS tiles ready

    const bf16x8* pA = (const bf16x8*)sA;
    const bf16x8* pB = (const bf16x8*)sB;
    #pragma unroll
    for (int kk = 0; kk < 2; ++kk) {
      bf16x8 af[4], bfv[4];
      #pragma unroll
      for (int fi = 0; fi < 4; ++fi)
        af[fi] = pA[(wrow * 64 + fi * 16 + fr) * 8 + ((kk * 4 + fq) ^ (fr & 7))];
      #pragma unroll
      for (int fj = 0; fj < 4; ++fj)
        bfv[fj] = pB[(wcol * 64 + fj * 16 + fr) * 8 + ((kk * 4 + fq) ^ (fr & 7))];
      #pragma unroll
      for (int fi = 0; fi < 4; ++fi)
        #pragma unroll
        for (int fj = 0; fj < 4; ++fj)
          acc[fi][fj] = __builtin_amdgcn_mfma_f32_16x16x32_bf16(af[fi], bfv[fj], acc[fi][fj], 0, 0, 0);
    }
  }

  float g = 0.f;
  if (MODE == 2) g = gainp[0];

  #pragma unroll
  for (int fi = 0; fi < 4; ++fi) {
    #pragma unroll
    for (int fj = 0; fj < 4; ++fj) {
      #pragma unroll
      for (int jj = 0; jj < 4; ++jj) {
        const int gm = bm * 128 + wrow * 64 + fi * 16 + fq * 4 + jj;
        const int gn = bn * 128 + wcol * 64 + fj * 16 + fr;
        const float c = acc[fi][fj][jj];
        if constexpr (MODE == 0) {
          outp[(size_t)gm * ldo + gn] = f2b(c);
        } else if constexpr (MODE == 1) {
          const float y = MP_NEW * c + MP_RES * b2f(res[(size_t)gm * 512 + gn]);
          outp[(size_t)gm * ldo + gn] = f2b(y);
        } else {
          const float y = MP_NEW * (c * g) + MP_RES * b2f(res[(size_t)gm * 512 + gn]);
          outp[(size_t)gm * ldo + gn] = f2b(y);
        }
      }
    }
  }
}

extern "C" void kernel_launch(void* const* d_in, const int* in_sizes, int n_in,
                              void* d_out, int out_size, void* d_ws, size_t ws_size,
                              hipStream_t stream)
{
  const float* x     = (const float*)d_in[0];
  const float* wqkv  = (const float*)d_in[1];
  const float* wout  = (const float*)d_in[2];
  const float* mkv   = (const float*)d_in[3];
  const float* wproj = (const float*)d_in[4];
  const float* gain  = (const float*)d_in[5];
  float* out = (float*)d_out;

  // workspace layout (bytes), total 96,993,280 (< proven-available 117,964,800)
  char* ws = (char*)d_ws;
  __hip_bfloat16* Y0   = (__hip_bfloat16*)(ws + 0);           // 33,554,432
  __hip_bfloat16* Ycur = (__hip_bfloat16*)(ws + 33554432);    // 33,554,432
  __hip_bfloat16* QKVc = (__hip_bfloat16*)(ws + 67108864);    // 25,165,824 (8192x1536 bf16)
  __hip_bfloat16* WQ   = (__hip_bfloat16*)(ws + 92274688);    //  3,145,728
  __hip_bfloat16* WO   = (__hip_bfloat16*)(ws + 95420416);    //  1,048,576
  __hip_bfloat16* WP   = (__hip_bfloat16*)(ws + 96468992);    //    524,288

  if (ws_size < 96993280ULL) {
    fill_kernel<<<(out_size + 255) / 256, 256, 0, stream>>>(out, out_size);
    return;
  }

  // normalize all weight rows (f32 -> bf16); both layers contiguous -> one call each
  wnorm_pack<<<3072, 64, 0, stream>>>(wqkv,  WQ);
  wnorm_pack<<<1024, 64, 0, stream>>>(wout,  WO);
  wnorm_pack<<<512,  64, 0, stream>>>(wproj, WP);

  // x (f32) -> token-major bf16
  transpose_in<<<dim3(32, 16, 32), dim3(32, 8), 0, stream>>>(x, Y0);

  const int M = 32768, CH = 8192, NCH = M / CH;
  for (int layer = 0; layer < 2; ++layer) {
    const __hip_bfloat16* WQl = WQ + (size_t)layer * 786432;
    const __hip_bfloat16* WOl = WO + (size_t)layer * 262144;
    const float* mk = mkv + (size_t)layer * 4096;
    __hip_bfloat16* Acur = (layer == 0) ? Y0 : Ycur;
    for (int ch = 0; ch < NCH; ++ch) {
      const size_t m0 = (size_t)ch * CH;
      // QKV: [CH x 1536] bf16
      gemm3<0><<<dim3(12, CH / 128), 256, 0, stream>>>(Acur + m0 * 512, WQl, 512,
                                                       QKVc, 1536, nullptr, nullptr);
      // attention in-place into q-cols
      attn_kernel<<<(CH / 16) * 8, 64, 0, stream>>>(QKVc, mk);
      // out-proj + mp_add -> Ycur chunk (A = q-cols of QKVc, lda=1536)
      gemm3<1><<<dim3(4, CH / 128), 256, 0, stream>>>(QKVc, WOl, 1536,
                                                      Ycur + m0 * 512, 512,
                                                      Acur + m0 * 512, nullptr);
    }
  }

  // final: Y0 = mp_add(proj(Ycur)*gain, Y0)  (in-place safe: same-thread r/w per element)
  gemm3<2><<<dim3(4, 256), 256, 0, stream>>>(Ycur, WP, 512, Y0, 512, Y0, gain);
  transpose_out<<<dim3(32, 16, 32), dim3(32, 8), 0, stream>>>(Y0, out);
}